// Round 17
// baseline (167.621 us; speedup 1.0000x reference)
//
#include <hip/hip_runtime.h>
#include <hip/hip_bf16.h>

typedef __bf16 bf16_t;
typedef __bf16 bf16x8 __attribute__((ext_vector_type(8)));
typedef __bf16 bf16x4 __attribute__((ext_vector_type(4)));
typedef float f32x4 __attribute__((ext_vector_type(4)));

#define SEQ_T 2048
#define DMODEL 2048
#define NQH 16
#define NKVH 4
#define HDIM 128

__device__ __forceinline__ f32x4 mfma16x16x32(bf16x8 a, bf16x8 b, f32x4 c) {
  return __builtin_amdgcn_mfma_f32_16x16x32_bf16(a, b, c, 0, 0, 0);
}

typedef __attribute__((address_space(3))) void lds_void_t;
typedef __attribute__((address_space(1))) const void gbl_void_t;
__device__ __forceinline__ void gload_lds16(const bf16_t* g, bf16_t* l) {
  __builtin_amdgcn_global_load_lds((gbl_void_t*)g, (lds_void_t*)l, 16, 0, 0);
}
__device__ __forceinline__ void BAR() {
  asm volatile("" ::: "memory");
  __builtin_amdgcn_s_barrier();
  asm volatile("" ::: "memory");
}

// ------- fused cast f32 -> bf16 for all 5 inputs + RoPE cos/sin table -------
// vec8 ranges: x[0,1048576) Wq[,1572864) Wk[,1703936) Wv[,1835008) Wo[,2359296)
// then 131072 threads build tab[2048][64].
__global__ __launch_bounds__(256) void cast_all(const float* __restrict__ x,
                                                const float* __restrict__ Wq,
                                                const float* __restrict__ Wk,
                                                const float* __restrict__ Wv,
                                                const float* __restrict__ Wo,
                                                bf16_t* __restrict__ xb,
                                                bf16_t* __restrict__ Wqkvb,
                                                bf16_t* __restrict__ Wob,
                                                float2* __restrict__ tab) {
  const int idx = blockIdx.x * 256 + threadIdx.x;
  if (idx >= 2359296) {  // sincos tail
    const int idx2 = idx - 2359296;
    const int t = idx2 >> 6, i = idx2 & 63;
    float inv = exp2f((float)i * (-13.287712379549449f / 64.0f));  // 10000^(-i/64)
    float ang = (float)t * inv;
    float s, c;
    sincosf(ang, &s, &c);
    tab[idx2] = make_float2(c, s);
    return;
  }
  const float* src;
  bf16_t* dst;
  if (idx < 1048576) {
    src = x + (size_t)idx * 8;
    dst = xb + (size_t)idx * 8;
  } else if (idx < 1572864) {
    const int r = idx - 1048576;
    src = Wq + (size_t)r * 8;
    dst = Wqkvb + (size_t)r * 8;
  } else if (idx < 1703936) {
    const int r = idx - 1572864;
    src = Wk + (size_t)r * 8;
    dst = Wqkvb + 4194304 + (size_t)r * 8;
  } else if (idx < 1835008) {
    const int r = idx - 1703936;
    src = Wv + (size_t)r * 8;
    dst = Wqkvb + 5242880 + (size_t)r * 8;
  } else {
    const int r = idx - 1835008;
    src = Wo + (size_t)r * 8;
    dst = Wob + (size_t)r * 8;
  }
  const float4* s4 = reinterpret_cast<const float4*>(src);
  float4 a = s4[0], b = s4[1];
  bf16x8 r8 = {(bf16_t)a.x, (bf16_t)a.y, (bf16_t)a.z, (bf16_t)a.w,
               (bf16_t)b.x, (bf16_t)b.y, (bf16_t)b.z, (bf16_t)b.w};
  *reinterpret_cast<bf16x8*>(dst) = r8;
}

// ---------------- QKV GEMM: 256x192 tile, grid 256 = exact CU cover ----------
// Single-barrier K-loop; intra-tile split: {B+A0 reads -> 24 MFMA -> A1 reads
// -> 24 MFMA} to shorten first-MFMA dependency and stagger LDS bursts.
__global__ __launch_bounds__(512, 2) void gemm_qkv(const bf16_t* __restrict__ A,
                                                   const bf16_t* __restrict__ W,
                                                   bf16_t* __restrict__ q_out,
                                                   bf16_t* __restrict__ k_out,
                                                   bf16_t* __restrict__ v_out,
                                                   const float2* __restrict__ tab) {
  constexpr int K = 2048;
  constexpr int NT = 32;
  const int id = ((int)blockIdx.x & 7) * 32 + ((int)blockIdx.x >> 3);  // XCD swizzle
  const int m0 = (id >> 4) * 256, n0 = (id & 15) * 192;
  const int tid = threadIdx.x;
  const int lane = tid & 63, w = tid >> 6;
  const int wr = w >> 2, wc = w & 3;
  const int l15 = lane & 15, g = lane >> 4;
  __shared__ bf16_t smem[2][(256 + 192) * 64];
  f32x4 acc[8][3] = {};
  bf16x8 af[4][2], bfr[3][2];

  auto ISSUE_ALL = [&](int tt) {
#pragma unroll
    for (int h = 0; h < 2; h++) {
      bf16_t* base = &smem[tt & 1][0] + h * (128 * 64);
      const bf16_t* src = A + (size_t)(m0 + h * 128) * K + tt * 64;
#pragma unroll
      for (int i = 0; i < 2; i++) {
        const int rl = i * 64 + (tid >> 3);
        gload_lds16(src + (size_t)rl * K + (((tid & 7) ^ (rl & 7)) << 3),
                    base + (i * 64 + w * 8) * 64);
      }
    }
#pragma unroll
    for (int c = 0; c < 3; c++) {
      bf16_t* base = &smem[tt & 1][0] + (256 + c * 64) * 64;
      const int rl = tid >> 3;
      const bf16_t* src = W + (size_t)(n0 + c * 64 + rl) * K + tt * 64;
      gload_lds16(src + (((tid & 7) ^ (rl & 7)) << 3), base + (w * 8) * 64);
    }
  };
  auto RDA = [&](const bf16_t* Ab, int qm) {
#pragma unroll
    for (int fi = 0; fi < 4; fi++) {
      const int row = wr * 128 + qm * 64 + fi * 16 + l15;
#pragma unroll
      for (int ksl = 0; ksl < 2; ksl++)
        af[fi][ksl] = *reinterpret_cast<const bf16x8*>(
            Ab + row * 64 + ((((ksl << 2) + g) ^ (row & 7)) << 3));
    }
  };

  ISSUE_ALL(0);

  for (int t = 0; t < NT; t++) {
    const bf16_t* Ab = &smem[t & 1][0];
    const bf16_t* Bb = Ab + 256 * 64;
    asm volatile("s_waitcnt vmcnt(0)" ::: "memory");  // tile t landed (issued 1 tile ago)
    BAR();
    if (t + 1 < NT) ISSUE_ALL(t + 1);
    // half 0: B frags + A(qm=0) frags, then their MFMAs
#pragma unroll
    for (int fj = 0; fj < 3; fj++) {
      const int row = wc * 48 + fj * 16 + l15;
#pragma unroll
      for (int ksl = 0; ksl < 2; ksl++)
        bfr[fj][ksl] = *reinterpret_cast<const bf16x8*>(
            Bb + row * 64 + ((((ksl << 2) + g) ^ (row & 7)) << 3));
    }
    RDA(Ab, 0);
    __builtin_amdgcn_s_setprio(1);
#pragma unroll
    for (int fi = 0; fi < 4; fi++)
#pragma unroll
      for (int fj = 0; fj < 3; fj++)
#pragma unroll
        for (int ksl = 0; ksl < 2; ksl++)
          acc[fi][fj] = mfma16x16x32(af[fi][ksl], bfr[fj][ksl], acc[fi][fj]);
    __builtin_amdgcn_s_setprio(0);
    // half 1: A(qm=1) frags, then their MFMAs
    RDA(Ab, 1);
    __builtin_amdgcn_s_setprio(1);
#pragma unroll
    for (int fi = 0; fi < 4; fi++)
#pragma unroll
      for (int fj = 0; fj < 3; fj++)
#pragma unroll
        for (int ksl = 0; ksl < 2; ksl++)
          acc[4 + fi][fj] = mfma16x16x32(af[fi][ksl], bfr[fj][ksl], acc[4 + fi][fj]);
    __builtin_amdgcn_s_setprio(0);
  }

#pragma unroll
  for (int fm = 0; fm < 8; fm++) {
    const int r0 = m0 + wr * 128 + fm * 16 + (g << 2);
    const int bb = r0 >> 11;
    const int tt = r0 & 2047;
#pragma unroll
    for (int fn = 0; fn < 3; fn++) {
      const int col = n0 + wc * 48 + fn * 16 + l15;
      const f32x4 v = acc[fm][fn];
      if (col < 2048) {  // Q region, RoPE fused
        const int dd = col & 127;
        const float2* tp = tab + (size_t)tt * 64 + (dd >> 1);
        bf16_t* dst = q_out + (((size_t)(bb * NQH + (col >> 7)) * SEQ_T + tt) * HDIM + dd);
#pragma unroll
        for (int i = 0; i < 4; i++) {
          float me = v[i];
          float ot = __shfl_xor(me, 1);
          float2 cs = tp[(size_t)i * 64];
          float r = (dd & 1) ? (me * cs.x + ot * cs.y) : (me * cs.x - ot * cs.y);
          dst[(size_t)i * HDIM] = (bf16_t)r;
        }
      } else if (col < 2560) {  // K region, RoPE fused
        const int dd = col & 127;
        const float2* tp = tab + (size_t)tt * 64 + (dd >> 1);
        bf16_t* dst = k_out + (((size_t)(bb * NKVH + ((col - 2048) >> 7)) * SEQ_T + tt) * HDIM + dd);
#pragma unroll
        for (int i = 0; i < 4; i++) {
          float me = v[i];
          float ot = __shfl_xor(me, 1);
          float2 cs = tp[(size_t)i * 64];
          float r = (dd & 1) ? (me * cs.x + ot * cs.y) : (me * cs.x - ot * cs.y);
          dst[(size_t)i * HDIM] = (bf16_t)r;
        }
      } else {  // V -> transposed [B,KVh,128,T'] with 64-granular kv-permutation
        const int vc = col - 2560;
        const int hh = vc >> 7, dd = vc & 127;
        const int tp64 = (tt & ~63) | (((tt >> 2) & 3) << 4) | (((tt >> 4) & 3) << 2);
        bf16x4 pk = {(bf16_t)v[0], (bf16_t)v[1], (bf16_t)v[2], (bf16_t)v[3]};
        *reinterpret_cast<bf16x4*>(v_out + (((size_t)(bb * NKVH + hh) * HDIM + dd) * SEQ_T + tp64)) = pk;
      }
    }
  }
}

// ---------------- Out GEMM: 256x128 tile, grid 256; single-barrier K-loop ----
__global__ __launch_bounds__(512, 2) void gemm_out(const bf16_t* __restrict__ A,
                                                   const bf16_t* __restrict__ W,
                                                   float* __restrict__ c_out) {
  constexpr int K = 2048;
  constexpr int NT = 32;
  const int id = ((int)blockIdx.x & 7) * 32 + ((int)blockIdx.x >> 3);
  const int m0 = (id >> 4) * 256, n0 = (id & 15) * 128;
  const int tid = threadIdx.x;
  const int lane = tid & 63, w = tid >> 6;
  const int wr = w >> 2, wc = w & 3;
  const int l15 = lane & 15, g = lane >> 4;
  __shared__ bf16_t smem[2][(256 + 128) * 64];
  f32x4 acc[8][2] = {};
  bf16x8 af[4][2], bfr[2][2];

  auto ISSUE_ALL = [&](int tt) {
    const int k0 = tt * 64;
#pragma unroll
    for (int h = 0; h < 3; h++) {
      bf16_t* base = &smem[tt & 1][0] + ((h < 2) ? h * (128 * 64) : 256 * 64);
      const bf16_t* src = (h < 2) ? (A + (size_t)(m0 + h * 128) * K)
                                  : (W + (size_t)n0 * K);
#pragma unroll
      for (int i = 0; i < 2; i++) {
        const int rl = i * 64 + (tid >> 3);
        gload_lds16(src + (size_t)rl * K + k0 + (((tid & 7) ^ (rl & 7)) << 3),
                    base + (i * 64 + w * 8) * 64);
      }
    }
  };
  auto RDA = [&](const bf16_t* Ab, int qm) {
#pragma unroll
    for (int fi = 0; fi < 4; fi++) {
      const int row = wr * 128 + qm * 64 + fi * 16 + l15;
#pragma unroll
      for (int ksl = 0; ksl < 2; ksl++)
        af[fi][ksl] = *reinterpret_cast<const bf16x8*>(
            Ab + row * 64 + ((((ksl << 2) + g) ^ (row & 7)) << 3));
    }
  };

  ISSUE_ALL(0);

  for (int t = 0; t < NT; t++) {
    const bf16_t* Ab = &smem[t & 1][0];
    const bf16_t* Bb = Ab + 256 * 64;
    asm volatile("s_waitcnt vmcnt(0)" ::: "memory");
    BAR();
    if (t + 1 < NT) ISSUE_ALL(t + 1);
    // half 0
#pragma unroll
    for (int qn = 0; qn < 2; qn++) {
      const int row = wc * 32 + qn * 16 + l15;
#pragma unroll
      for (int ksl = 0; ksl < 2; ksl++)
        bfr[qn][ksl] = *reinterpret_cast<const bf16x8*>(
            Bb + row * 64 + ((((ksl << 2) + g) ^ (row & 7)) << 3));
    }
    RDA(Ab, 0);
    __builtin_amdgcn_s_setprio(1);
#pragma unroll
    for (int fi = 0; fi < 4; fi++)
#pragma unroll
      for (int qn = 0; qn < 2; qn++)
#pragma unroll
        for (int ksl = 0; ksl < 2; ksl++)
          acc[fi][qn] = mfma16x16x32(af[fi][ksl], bfr[qn][ksl], acc[fi][qn]);
    __builtin_amdgcn_s_setprio(0);
    // half 1
    RDA(Ab, 1);
    __builtin_amdgcn_s_setprio(1);
#pragma unroll
    for (int fi = 0; fi < 4; fi++)
#pragma unroll
      for (int qn = 0; qn < 2; qn++)
#pragma unroll
        for (int ksl = 0; ksl < 2; ksl++)
          acc[4 + fi][qn] = mfma16x16x32(af[fi][ksl], bfr[qn][ksl], acc[4 + fi][qn]);
    __builtin_amdgcn_s_setprio(0);
  }

#pragma unroll
  for (int fm = 0; fm < 8; fm++) {
    const int r0 = m0 + wr * 128 + fm * 16 + (g << 2);
#pragma unroll
    for (int fn = 0; fn < 2; fn++) {
      const int col = n0 + wc * 32 + fn * 16 + l15;
#pragma unroll
      for (int i = 0; i < 4; i++) c_out[(size_t)(r0 + i) * 2048 + col] = acc[fm][fn][i];
    }
  }
}

// ---------------- Flash attention (causal GQA), static-max softmax ----------
// R15 structure + 1D grid with bijective XCD swizzle (same-XCD blocks share
// bh -> 4 KV streams = 4MB per XCD L2).
__global__ __launch_bounds__(256, 2) void attn_kernel(const bf16_t* __restrict__ Qb,
                                                      const bf16_t* __restrict__ Kb,
                                                      const bf16_t* __restrict__ Vt,
                                                      bf16_t* __restrict__ AO) {
  const int id = ((int)blockIdx.x & 7) * 64 + ((int)blockIdx.x >> 3);  // XCD swizzle (512)
  const int bh = id >> 4;
  const int b = bh >> 4, h = bh & 15, kvh = h >> 2;
  const int p = id & 15;  // 0..15
  const int jH = 31 - p, jL = p;
  const int q0H = jH * 64, q0L = jL * 64;
  const int tid = threadIdx.x;
  const int lane = tid & 63, w = tid >> 6;  // 4 waves
  const bf16_t* Qp = Qb + (size_t)(b * NQH + h) * SEQ_T * HDIM;
  const bf16_t* Kp = Kb + (size_t)(b * NKVH + kvh) * SEQ_T * HDIM;
  const bf16_t* Vp = Vt + (size_t)(b * NKVH + kvh) * HDIM * SEQ_T;
  __shared__ bf16_t smem[2][16384];  // per buf: Ks [64][128] | Vs [128][64]
  const int l15 = lane & 15, g = lane >> 4;
  const int qrA = q0H + w * 16 + l15;  // heavy-tile q-row
  const int qrB = q0L + w * 16 + l15;  // light-tile q-row
  const float kscale = 0.08838834764831845f * 1.4426950408889634f;  // 1/sqrt(128)*log2e
  bf16x8 qfA[4], qfB[4];
#pragma unroll
  for (int c = 0; c < 4; c++) {
    qfA[c] = *reinterpret_cast<const bf16x8*>(Qp + (size_t)qrA * HDIM + c * 32 + (g << 3));
    qfB[c] = *reinterpret_cast<const bf16x8*>(Qp + (size_t)qrB * HDIM + c * 32 + (g << 3));
#pragma unroll
    for (int e = 0; e < 8; e++) {  // pre-scale Q by kscale (once)
      qfA[c][e] = (bf16_t)((float)qfA[c][e] * kscale);
      qfB[c][e] = (bf16_t)((float)qfB[c][e] * kscale);
    }
  }
  f32x4 oA[8] = {}, oB[8] = {};
  float lA = 0.0f, lB = 0.0f;  // per-lane partial denominators
  const int wmaxB = q0L + w * 16 + 15;
  const int ntiles = jH + 1;  // KVBLK=64 tiles staged

  auto STAGE = [&](int it, int buf) {
    const int kv0s = it * 64;
    bf16_t* Ks = smem[buf];
    bf16_t* Vs = smem[buf] + 8192;
#pragma unroll
    for (int cc = 0; cc < 4; cc++) {
      const int ck = cc * 256 + tid;
      const int krow = ck >> 4, kg = ck & 15;
      gload_lds16(Kp + (size_t)(kv0s + krow) * HDIM + ((kg ^ (krow & 7)) << 3),
                  Ks + (cc * 256 + w * 64) * 8);
      const int vrow = ck >> 3, vg = ck & 7;
      gload_lds16(Vp + (size_t)vrow * SEQ_T + kv0s + ((vg ^ (vrow & 7)) << 3),
                  Vs + (cc * 256 + w * 64) * 8);
    }
  };

  // static-max: exp2 all 16 (log2 domain already), accumulate per-lane l, pack
  auto PEXP = [&](float* sv, float& l, bf16x8* pc) {
#pragma unroll
    for (int j = 0; j < 16; j++) sv[j] = exp2f(sv[j]);
    float r0 = (sv[0] + sv[1]) + (sv[2] + sv[3]);
    float r1 = (sv[4] + sv[5]) + (sv[6] + sv[7]);
    float r2 = (sv[8] + sv[9]) + (sv[10] + sv[11]);
    float r3 = (sv[12] + sv[13]) + (sv[14] + sv[15]);
    l += (r0 + r1) + (r2 + r3);
#pragma unroll
    for (int s = 0; s < 2; s++) {
      bf16x8 t = {(bf16_t)sv[8 * s],     (bf16_t)sv[8 * s + 1], (bf16_t)sv[8 * s + 2],
                  (bf16_t)sv[8 * s + 3], (bf16_t)sv[8 * s + 4], (bf16_t)sv[8 * s + 5],
                  (bf16_t)sv[8 * s + 6], (bf16_t)sv[8 * s + 7]};
      pc[s] = t;
    }
  };

  auto COMPUTE1 = [&](const bf16_t* Ks, const bf16_t* Vs, int kv0) {
    float sv[16];
    const bool noMask = (kv0 + 63 <= q0H + w * 16);
    __builtin_amdgcn_s_setprio(1);
#pragma unroll
    for (int ksub = 0; ksub < 4; ksub++) {
      f32x4 sa = {};
      const int krow = ksub * 16 + l15;
#pragma unroll
      for (int ch = 0; ch < 4; ch++) {
        bf16x8 kf = *reinterpret_cast<const bf16x8*>(
            Ks + krow * 128 + ((((ch << 2) + g) ^ (krow & 7)) << 3));
        sa = mfma16x16x32(kf, qfA[ch], sa);
      }
      if (noMask) {
#pragma unroll
        for (int i = 0; i < 4; i++) sv[ksub * 4 + i] = sa[i];
      } else {
        const int dlt = qrA - kv0 - ksub * 16 - (g << 2);
#pragma unroll
        for (int i = 0; i < 4; i++) sv[ksub * 4 + i] = (i <= dlt) ? sa[i] : -3e38f;
      }
    }
    __builtin_amdgcn_s_setprio(0);
    bf16x8 pc[2];
    PEXP(sv, lA, pc);
    __builtin_amdgcn_s_setprio(1);
#pragma unroll
    for (int dt = 0; dt < 8; dt++) {
      const int vrow = dt * 16 + l15;
#pragma unroll
      for (int s = 0; s < 2; s++) {
        bf16x8 vv = *reinterpret_cast<const bf16x8*>(
            Vs + vrow * 64 + (((2 * g + s) ^ (vrow & 7)) << 3));
        oA[dt] = mfma16x16x32(vv, pc[s], oA[dt]);
      }
    }
    __builtin_amdgcn_s_setprio(0);
  };

  auto COMPUTE2 = [&](const bf16_t* Ks, const bf16_t* Vs, int kv0) {
    float svA[16], svB[16];
    const bool noMaskB = (kv0 + 63 <= q0L + w * 16);
    __builtin_amdgcn_s_setprio(1);
#pragma unroll
    for (int ksub = 0; ksub < 4; ksub++) {
      f32x4 sa = {}, sb = {};
      const int krow = ksub * 16 + l15;
#pragma unroll
      for (int ch = 0; ch < 4; ch++) {
        bf16x8 kf = *reinterpret_cast<const bf16x8*>(
            Ks + krow * 128 + ((((ch << 2) + g) ^ (krow & 7)) << 3));
        sa = mfma16x16x32(kf, qfA[ch], sa);
        sb = mfma16x16x32(kf, qfB[ch], sb);
      }
#pragma unroll
      for (int i = 0; i < 4; i++) svA[ksub * 4 + i] = sa[i];
      if (noMaskB) {
#pragma unroll
        for (int i = 0; i < 4; i++) svB[ksub * 4 + i] = sb[i];
      } else {
        const int dltB = qrB - kv0 - ksub * 16 - (g << 2);
#pragma unroll
        for (int i = 0; i < 4; i++) svB[ksub * 4 + i] = (i <= dltB) ? sb[i] : -3e38f;
      }
    }
    __builtin_amdgcn_s_setprio(0);
    bf16x8 pcA[2], pcB[2];
    PEXP(svA, lA, pcA);
    PEXP(svB, lB, pcB);
    __builtin_amdgcn_s_setprio(1);
#pragma unroll
    for (int dt = 0; dt < 8; dt++) {
      const int vrow = dt * 16 + l15;
#pragma unroll
      for (int s = 0; s < 2; s++) {
        bf16x8 vv = *reinterpret_cast<const bf16x8*>(
            Vs + vrow * 64 + (((2 * g + s) ^ (vrow & 7)) << 3));
        oA[dt] = mfma16x16x32(vv, pcA[s], oA[dt]);
        oB[dt] = mfma16x16x32(vv, pcB[s], oB[dt]);
      }
    }
    __builtin_amdgcn_s_setprio(0);
  };

  STAGE(0, 0);
  for (int it = 0; it < ntiles; it++) {
    const int buf = it & 1;
    asm volatile("s_waitcnt vmcnt(0)" ::: "memory");
    BAR();
    if (it + 1 < ntiles) STAGE(it + 1, buf ^ 1);
    const int kv0 = it * 64;
    const bf16_t* Ks = smem[buf];
    const bf16_t* Vs = smem[buf] + 8192;
    if (kv0 <= wmaxB) {
      COMPUTE2(Ks, Vs, kv0);  // B active => A active & unmasked
    } else {
      COMPUTE1(Ks, Vs, kv0);
    }
  }
  BAR();  // all waves done with smem before epilogue reuses it
  bf16_t* os = &smem[0][0] + w * 2048;
  auto EPI = [&](f32x4* o, float lsum, int q0) {
    lsum += __shfl_xor(lsum, 16, 64);
    lsum += __shfl_xor(lsum, 32, 64);
    const float linv = 1.0f / lsum;
#pragma unroll
    for (int dt = 0; dt < 8; dt++) {
      bf16x4 pk = {(bf16_t)(o[dt][0] * linv), (bf16_t)(o[dt][1] * linv),
                   (bf16_t)(o[dt][2] * linv), (bf16_t)(o[dt][3] * linv)};
      *reinterpret_cast<bf16x4*>(os + l15 * 128 + dt * 16 + (g << 2)) = pk;
    }
    const size_t rowb = (size_t)b * SEQ_T + q0 + w * 16;
#pragma unroll
    for (int kk = 0; kk < 4; kk++) {
      const int c = lane + kk * 64;
      const int q = c >> 4, gc = c & 15;
      *reinterpret_cast<bf16x8*>(AO + (rowb + q) * DMODEL + h * HDIM + gc * 8) =
          *reinterpret_cast<const bf16x8*>(os + q * 128 + gc * 8);
    }
  };
  EPI(oA, lA, q0H);
  EPI(oB, lB, q0L);
}

extern "C" void kernel_launch(void* const* d_in, const int* in_sizes, int n_in,
                              void* d_out, int out_size, void* d_ws, size_t ws_size,
                              hipStream_t stream) {
  const float* x = (const float*)d_in[0];
  const float* Wq = (const float*)d_in[1];
  const float* Wk = (const float*)d_in[2];
  const float* Wv = (const float*)d_in[3];
  const float* Wo = (const float*)d_in[4];
  float* out = (float*)d_out;
  char* ws = (char*)d_ws;
  bf16_t* xb = (bf16_t*)(ws);                         // [4096][2048]        16 MB
  bf16_t* Wqkvb = (bf16_t*)(ws + 16777216);           // [3072][2048]        12 MB
  bf16_t* Wob = (bf16_t*)(ws + 29360128);             // [2048][2048]         8 MB
  bf16_t* Qb = (bf16_t*)(ws + 37748736);              // [2][16][2048][128]  16 MB
  bf16_t* Kb = (bf16_t*)(ws + 54525952);              // [2][4][2048][128]    4 MB
  bf16_t* Vt = (bf16_t*)(ws + 58720256);              // [2][4][128][2048]    4 MB (tp64 perm)
  bf16_t* AO = (bf16_t*)(ws + 62914560);              // [4096][2048]        16 MB
  float2* tab = (float2*)(ws + 79691776);             // [2048][64]           1 MB

  cast_all<<<9728, 256, 0, stream>>>(x, Wq, Wk, Wv, Wo, xb, Wqkvb, Wob, tab);
  gemm_qkv<<<256, 512, 0, stream>>>(xb, Wqkvb, Qb, Kb, Vt, tab);
  attn_kernel<<<512, 256, 0, stream>>>(Qb, Kb, Vt, AO);
  gemm_out<<<256, 512, 0, stream>>>(AO, Wob, out);
}

// Round 18
// 161.970 us; speedup vs baseline: 1.0349x; 1.0349x over previous
//
#include <hip/hip_runtime.h>
#include <hip/hip_bf16.h>

typedef __bf16 bf16_t;
typedef __bf16 bf16x8 __attribute__((ext_vector_type(8)));
typedef __bf16 bf16x4 __attribute__((ext_vector_type(4)));
typedef float f32x4 __attribute__((ext_vector_type(4)));

#define SEQ_T 2048
#define DMODEL 2048
#define NQH 16
#define NKVH 4
#define HDIM 128

__device__ __forceinline__ f32x4 mfma16x16x32(bf16x8 a, bf16x8 b, f32x4 c) {
  return __builtin_amdgcn_mfma_f32_16x16x32_bf16(a, b, c, 0, 0, 0);
}

typedef __attribute__((address_space(3))) void lds_void_t;
typedef __attribute__((address_space(1))) const void gbl_void_t;
__device__ __forceinline__ void gload_lds16(const bf16_t* g, bf16_t* l) {
  __builtin_amdgcn_global_load_lds((gbl_void_t*)g, (lds_void_t*)l, 16, 0, 0);
}
__device__ __forceinline__ void BAR() {
  asm volatile("" ::: "memory");
  __builtin_amdgcn_s_barrier();
  asm volatile("" ::: "memory");
}

// ------- fused cast f32 -> bf16 for all 5 inputs + RoPE cos/sin table -------
__global__ __launch_bounds__(256) void cast_all(const float* __restrict__ x,
                                                const float* __restrict__ Wq,
                                                const float* __restrict__ Wk,
                                                const float* __restrict__ Wv,
                                                const float* __restrict__ Wo,
                                                bf16_t* __restrict__ xb,
                                                bf16_t* __restrict__ Wqkvb,
                                                bf16_t* __restrict__ Wob,
                                                float2* __restrict__ tab) {
  const int idx = blockIdx.x * 256 + threadIdx.x;
  if (idx >= 2359296) {  // sincos tail
    const int idx2 = idx - 2359296;
    const int t = idx2 >> 6, i = idx2 & 63;
    float inv = exp2f((float)i * (-13.287712379549449f / 64.0f));  // 10000^(-i/64)
    float ang = (float)t * inv;
    float s, c;
    sincosf(ang, &s, &c);
    tab[idx2] = make_float2(c, s);
    return;
  }
  const float* src;
  bf16_t* dst;
  if (idx < 1048576) {
    src = x + (size_t)idx * 8;
    dst = xb + (size_t)idx * 8;
  } else if (idx < 1572864) {
    const int r = idx - 1048576;
    src = Wq + (size_t)r * 8;
    dst = Wqkvb + (size_t)r * 8;
  } else if (idx < 1703936) {
    const int r = idx - 1572864;
    src = Wk + (size_t)r * 8;
    dst = Wqkvb + 4194304 + (size_t)r * 8;
  } else if (idx < 1835008) {
    const int r = idx - 1703936;
    src = Wv + (size_t)r * 8;
    dst = Wqkvb + 5242880 + (size_t)r * 8;
  } else {
    const int r = idx - 1835008;
    src = Wo + (size_t)r * 8;
    dst = Wob + (size_t)r * 8;
  }
  const float4* s4 = reinterpret_cast<const float4*>(src);
  float4 a = s4[0], b = s4[1];
  bf16x8 r8 = {(bf16_t)a.x, (bf16_t)a.y, (bf16_t)a.z, (bf16_t)a.w,
               (bf16_t)b.x, (bf16_t)b.y, (bf16_t)b.z, (bf16_t)b.w};
  *reinterpret_cast<bf16x8*>(dst) = r8;
}

// ---------------- QKV GEMM: 256x192 tile, grid 256 = exact CU cover ----------
// Single-barrier K-loop; intra-tile split: {B+A0 reads -> 24 MFMA -> A1 reads
// -> 24 MFMA}.
__global__ __launch_bounds__(512, 2) void gemm_qkv(const bf16_t* __restrict__ A,
                                                   const bf16_t* __restrict__ W,
                                                   bf16_t* __restrict__ q_out,
                                                   bf16_t* __restrict__ k_out,
                                                   bf16_t* __restrict__ v_out,
                                                   const float2* __restrict__ tab) {
  constexpr int K = 2048;
  constexpr int NT = 32;
  const int id = ((int)blockIdx.x & 7) * 32 + ((int)blockIdx.x >> 3);  // XCD swizzle
  const int m0 = (id >> 4) * 256, n0 = (id & 15) * 192;
  const int tid = threadIdx.x;
  const int lane = tid & 63, w = tid >> 6;
  const int wr = w >> 2, wc = w & 3;
  const int l15 = lane & 15, g = lane >> 4;
  __shared__ bf16_t smem[2][(256 + 192) * 64];
  f32x4 acc[8][3] = {};
  bf16x8 af[4][2], bfr[3][2];

  auto ISSUE_ALL = [&](int tt) {
#pragma unroll
    for (int h = 0; h < 2; h++) {
      bf16_t* base = &smem[tt & 1][0] + h * (128 * 64);
      const bf16_t* src = A + (size_t)(m0 + h * 128) * K + tt * 64;
#pragma unroll
      for (int i = 0; i < 2; i++) {
        const int rl = i * 64 + (tid >> 3);
        gload_lds16(src + (size_t)rl * K + (((tid & 7) ^ (rl & 7)) << 3),
                    base + (i * 64 + w * 8) * 64);
      }
    }
#pragma unroll
    for (int c = 0; c < 3; c++) {
      bf16_t* base = &smem[tt & 1][0] + (256 + c * 64) * 64;
      const int rl = tid >> 3;
      const bf16_t* src = W + (size_t)(n0 + c * 64 + rl) * K + tt * 64;
      gload_lds16(src + (((tid & 7) ^ (rl & 7)) << 3), base + (w * 8) * 64);
    }
  };
  auto RDA = [&](const bf16_t* Ab, int qm) {
#pragma unroll
    for (int fi = 0; fi < 4; fi++) {
      const int row = wr * 128 + qm * 64 + fi * 16 + l15;
#pragma unroll
      for (int ksl = 0; ksl < 2; ksl++)
        af[fi][ksl] = *reinterpret_cast<const bf16x8*>(
            Ab + row * 64 + ((((ksl << 2) + g) ^ (row & 7)) << 3));
    }
  };

  ISSUE_ALL(0);

  for (int t = 0; t < NT; t++) {
    const bf16_t* Ab = &smem[t & 1][0];
    const bf16_t* Bb = Ab + 256 * 64;
    asm volatile("s_waitcnt vmcnt(0)" ::: "memory");  // tile t landed (issued 1 tile ago)
    BAR();
    if (t + 1 < NT) ISSUE_ALL(t + 1);
    // half 0: B frags + A(qm=0) frags, then their MFMAs
#pragma unroll
    for (int fj = 0; fj < 3; fj++) {
      const int row = wc * 48 + fj * 16 + l15;
#pragma unroll
      for (int ksl = 0; ksl < 2; ksl++)
        bfr[fj][ksl] = *reinterpret_cast<const bf16x8*>(
            Bb + row * 64 + ((((ksl << 2) + g) ^ (row & 7)) << 3));
    }
    RDA(Ab, 0);
    __builtin_amdgcn_s_setprio(1);
#pragma unroll
    for (int fi = 0; fi < 4; fi++)
#pragma unroll
      for (int fj = 0; fj < 3; fj++)
#pragma unroll
        for (int ksl = 0; ksl < 2; ksl++)
          acc[fi][fj] = mfma16x16x32(af[fi][ksl], bfr[fj][ksl], acc[fi][fj]);
    __builtin_amdgcn_s_setprio(0);
    // half 1: A(qm=1) frags, then their MFMAs
    RDA(Ab, 1);
    __builtin_amdgcn_s_setprio(1);
#pragma unroll
    for (int fi = 0; fi < 4; fi++)
#pragma unroll
      for (int fj = 0; fj < 3; fj++)
#pragma unroll
        for (int ksl = 0; ksl < 2; ksl++)
          acc[4 + fi][fj] = mfma16x16x32(af[fi][ksl], bfr[fj][ksl], acc[4 + fi][fj]);
    __builtin_amdgcn_s_setprio(0);
  }

#pragma unroll
  for (int fm = 0; fm < 8; fm++) {
    const int r0 = m0 + wr * 128 + fm * 16 + (g << 2);
    const int bb = r0 >> 11;
    const int tt = r0 & 2047;
#pragma unroll
    for (int fn = 0; fn < 3; fn++) {
      const int col = n0 + wc * 48 + fn * 16 + l15;
      const f32x4 v = acc[fm][fn];
      if (col < 2048) {  // Q region, RoPE fused
        const int dd = col & 127;
        const float2* tp = tab + (size_t)tt * 64 + (dd >> 1);
        bf16_t* dst = q_out + (((size_t)(bb * NQH + (col >> 7)) * SEQ_T + tt) * HDIM + dd);
#pragma unroll
        for (int i = 0; i < 4; i++) {
          float me = v[i];
          float ot = __shfl_xor(me, 1);
          float2 cs = tp[(size_t)i * 64];
          float r = (dd & 1) ? (me * cs.x + ot * cs.y) : (me * cs.x - ot * cs.y);
          dst[(size_t)i * HDIM] = (bf16_t)r;
        }
      } else if (col < 2560) {  // K region, RoPE fused
        const int dd = col & 127;
        const float2* tp = tab + (size_t)tt * 64 + (dd >> 1);
        bf16_t* dst = k_out + (((size_t)(bb * NKVH + ((col - 2048) >> 7)) * SEQ_T + tt) * HDIM + dd);
#pragma unroll
        for (int i = 0; i < 4; i++) {
          float me = v[i];
          float ot = __shfl_xor(me, 1);
          float2 cs = tp[(size_t)i * 64];
          float r = (dd & 1) ? (me * cs.x + ot * cs.y) : (me * cs.x - ot * cs.y);
          dst[(size_t)i * HDIM] = (bf16_t)r;
        }
      } else {  // V -> transposed [B,KVh,128,T'] with 64-granular kv-permutation
        const int vc = col - 2560;
        const int hh = vc >> 7, dd = vc & 127;
        const int tp64 = (tt & ~63) | (((tt >> 2) & 3) << 4) | (((tt >> 4) & 3) << 2);
        bf16x4 pk = {(bf16_t)v[0], (bf16_t)v[1], (bf16_t)v[2], (bf16_t)v[3]};
        *reinterpret_cast<bf16x4*>(v_out + (((size_t)(bb * NKVH + hh) * HDIM + dd) * SEQ_T + tp64)) = pk;
      }
    }
  }
}

// ---------------- Out GEMM: 256x128 tile, grid 256; single-barrier K-loop ----
__global__ __launch_bounds__(512, 2) void gemm_out(const bf16_t* __restrict__ A,
                                                   const bf16_t* __restrict__ W,
                                                   float* __restrict__ c_out) {
  constexpr int K = 2048;
  constexpr int NT = 32;
  const int id = ((int)blockIdx.x & 7) * 32 + ((int)blockIdx.x >> 3);
  const int m0 = (id >> 4) * 256, n0 = (id & 15) * 128;
  const int tid = threadIdx.x;
  const int lane = tid & 63, w = tid >> 6;
  const int wr = w >> 2, wc = w & 3;
  const int l15 = lane & 15, g = lane >> 4;
  __shared__ bf16_t smem[2][(256 + 128) * 64];
  f32x4 acc[8][2] = {};
  bf16x8 af[4][2], bfr[2][2];

  auto ISSUE_ALL = [&](int tt) {
    const int k0 = tt * 64;
#pragma unroll
    for (int h = 0; h < 3; h++) {
      bf16_t* base = &smem[tt & 1][0] + ((h < 2) ? h * (128 * 64) : 256 * 64);
      const bf16_t* src = (h < 2) ? (A + (size_t)(m0 + h * 128) * K)
                                  : (W + (size_t)n0 * K);
#pragma unroll
      for (int i = 0; i < 2; i++) {
        const int rl = i * 64 + (tid >> 3);
        gload_lds16(src + (size_t)rl * K + k0 + (((tid & 7) ^ (rl & 7)) << 3),
                    base + (i * 64 + w * 8) * 64);
      }
    }
  };
  auto RDA = [&](const bf16_t* Ab, int qm) {
#pragma unroll
    for (int fi = 0; fi < 4; fi++) {
      const int row = wr * 128 + qm * 64 + fi * 16 + l15;
#pragma unroll
      for (int ksl = 0; ksl < 2; ksl++)
        af[fi][ksl] = *reinterpret_cast<const bf16x8*>(
            Ab + row * 64 + ((((ksl << 2) + g) ^ (row & 7)) << 3));
    }
  };

  ISSUE_ALL(0);

  for (int t = 0; t < NT; t++) {
    const bf16_t* Ab = &smem[t & 1][0];
    const bf16_t* Bb = Ab + 256 * 64;
    asm volatile("s_waitcnt vmcnt(0)" ::: "memory");
    BAR();
    if (t + 1 < NT) ISSUE_ALL(t + 1);
    // half 0
#pragma unroll
    for (int qn = 0; qn < 2; qn++) {
      const int row = wc * 32 + qn * 16 + l15;
#pragma unroll
      for (int ksl = 0; ksl < 2; ksl++)
        bfr[qn][ksl] = *reinterpret_cast<const bf16x8*>(
            Bb + row * 64 + ((((ksl << 2) + g) ^ (row & 7)) << 3));
    }
    RDA(Ab, 0);
    __builtin_amdgcn_s_setprio(1);
#pragma unroll
    for (int fi = 0; fi < 4; fi++)
#pragma unroll
      for (int qn = 0; qn < 2; qn++)
#pragma unroll
        for (int ksl = 0; ksl < 2; ksl++)
          acc[fi][qn] = mfma16x16x32(af[fi][ksl], bfr[qn][ksl], acc[fi][qn]);
    __builtin_amdgcn_s_setprio(0);
    // half 1
    RDA(Ab, 1);
    __builtin_amdgcn_s_setprio(1);
#pragma unroll
    for (int fi = 0; fi < 4; fi++)
#pragma unroll
      for (int qn = 0; qn < 2; qn++)
#pragma unroll
        for (int ksl = 0; ksl < 2; ksl++)
          acc[4 + fi][qn] = mfma16x16x32(af[fi][ksl], bfr[qn][ksl], acc[4 + fi][qn]);
    __builtin_amdgcn_s_setprio(0);
  }

#pragma unroll
  for (int fm = 0; fm < 8; fm++) {
    const int r0 = m0 + wr * 128 + fm * 16 + (g << 2);
#pragma unroll
    for (int fn = 0; fn < 2; fn++) {
      const int col = n0 + wc * 32 + fn * 16 + l15;
#pragma unroll
      for (int i = 0; i < 4; i++) c_out[(size_t)(r0 + i) * 2048 + col] = acc[fm][fn][i];
    }
  }
}

// ---------------- Flash attention (causal GQA), static-max softmax ----------
// R15/R16 structure: 2D grid (bh, p) -> co-resident blocks share p => equal
// 33-tile workloads per CU (the R17 1D XCD swizzle broke this; reverted).
__global__ __launch_bounds__(256, 2) void attn_kernel(const bf16_t* __restrict__ Qb,
                                                      const bf16_t* __restrict__ Kb,
                                                      const bf16_t* __restrict__ Vt,
                                                      bf16_t* __restrict__ AO) {
  const int bh = blockIdx.x;
  const int b = bh >> 4, h = bh & 15, kvh = h >> 2;
  const int p = blockIdx.y;  // 0..15
  const int jH = 31 - p, jL = p;
  const int q0H = jH * 64, q0L = jL * 64;
  const int tid = threadIdx.x;
  const int lane = tid & 63, w = tid >> 6;  // 4 waves
  const bf16_t* Qp = Qb + (size_t)(b * NQH + h) * SEQ_T * HDIM;
  const bf16_t* Kp = Kb + (size_t)(b * NKVH + kvh) * SEQ_T * HDIM;
  const bf16_t* Vp = Vt + (size_t)(b * NKVH + kvh) * HDIM * SEQ_T;
  __shared__ bf16_t smem[2][16384];  // per buf: Ks [64][128] | Vs [128][64]
  const int l15 = lane & 15, g = lane >> 4;
  const int qrA = q0H + w * 16 + l15;  // heavy-tile q-row
  const int qrB = q0L + w * 16 + l15;  // light-tile q-row
  const float kscale = 0.08838834764831845f * 1.4426950408889634f;  // 1/sqrt(128)*log2e
  bf16x8 qfA[4], qfB[4];
#pragma unroll
  for (int c = 0; c < 4; c++) {
    qfA[c] = *reinterpret_cast<const bf16x8*>(Qp + (size_t)qrA * HDIM + c * 32 + (g << 3));
    qfB[c] = *reinterpret_cast<const bf16x8*>(Qp + (size_t)qrB * HDIM + c * 32 + (g << 3));
#pragma unroll
    for (int e = 0; e < 8; e++) {  // pre-scale Q by kscale (once)
      qfA[c][e] = (bf16_t)((float)qfA[c][e] * kscale);
      qfB[c][e] = (bf16_t)((float)qfB[c][e] * kscale);
    }
  }
  f32x4 oA[8] = {}, oB[8] = {};
  float lA = 0.0f, lB = 0.0f;  // per-lane partial denominators
  const int wmaxB = q0L + w * 16 + 15;
  const int ntiles = jH + 1;  // KVBLK=64 tiles staged

  auto STAGE = [&](int it, int buf) {
    const int kv0s = it * 64;
    bf16_t* Ks = smem[buf];
    bf16_t* Vs = smem[buf] + 8192;
#pragma unroll
    for (int cc = 0; cc < 4; cc++) {
      const int ck = cc * 256 + tid;
      const int krow = ck >> 4, kg = ck & 15;
      gload_lds16(Kp + (size_t)(kv0s + krow) * HDIM + ((kg ^ (krow & 7)) << 3),
                  Ks + (cc * 256 + w * 64) * 8);
      const int vrow = ck >> 3, vg = ck & 7;
      gload_lds16(Vp + (size_t)vrow * SEQ_T + kv0s + ((vg ^ (vrow & 7)) << 3),
                  Vs + (cc * 256 + w * 64) * 8);
    }
  };

  // static-max: exp2 all 16 (log2 domain already), accumulate per-lane l, pack
  auto PEXP = [&](float* sv, float& l, bf16x8* pc) {
#pragma unroll
    for (int j = 0; j < 16; j++) sv[j] = exp2f(sv[j]);
    float r0 = (sv[0] + sv[1]) + (sv[2] + sv[3]);
    float r1 = (sv[4] + sv[5]) + (sv[6] + sv[7]);
    float r2 = (sv[8] + sv[9]) + (sv[10] + sv[11]);
    float r3 = (sv[12] + sv[13]) + (sv[14] + sv[15]);
    l += (r0 + r1) + (r2 + r3);
#pragma unroll
    for (int s = 0; s < 2; s++) {
      bf16x8 t = {(bf16_t)sv[8 * s],     (bf16_t)sv[8 * s + 1], (bf16_t)sv[8 * s + 2],
                  (bf16_t)sv[8 * s + 3], (bf16_t)sv[8 * s + 4], (bf16_t)sv[8 * s + 5],
                  (bf16_t)sv[8 * s + 6], (bf16_t)sv[8 * s + 7]};
      pc[s] = t;
    }
  };

  auto COMPUTE1 = [&](const bf16_t* Ks, const bf16_t* Vs, int kv0) {
    float sv[16];
    const bool noMask = (kv0 + 63 <= q0H + w * 16);
    __builtin_amdgcn_s_setprio(1);
#pragma unroll
    for (int ksub = 0; ksub < 4; ksub++) {
      f32x4 sa = {};
      const int krow = ksub * 16 + l15;
#pragma unroll
      for (int ch = 0; ch < 4; ch++) {
        bf16x8 kf = *reinterpret_cast<const bf16x8*>(
            Ks + krow * 128 + ((((ch << 2) + g) ^ (krow & 7)) << 3));
        sa = mfma16x16x32(kf, qfA[ch], sa);
      }
      if (noMask) {
#pragma unroll
        for (int i = 0; i < 4; i++) sv[ksub * 4 + i] = sa[i];
      } else {
        const int dlt = qrA - kv0 - ksub * 16 - (g << 2);
#pragma unroll
        for (int i = 0; i < 4; i++) sv[ksub * 4 + i] = (i <= dlt) ? sa[i] : -3e38f;
      }
    }
    __builtin_amdgcn_s_setprio(0);
    bf16x8 pc[2];
    PEXP(sv, lA, pc);
    __builtin_amdgcn_s_setprio(1);
#pragma unroll
    for (int dt = 0; dt < 8; dt++) {
      const int vrow = dt * 16 + l15;
#pragma unroll
      for (int s = 0; s < 2; s++) {
        bf16x8 vv = *reinterpret_cast<const bf16x8*>(
            Vs + vrow * 64 + (((2 * g + s) ^ (vrow & 7)) << 3));
        oA[dt] = mfma16x16x32(vv, pc[s], oA[dt]);
      }
    }
    __builtin_amdgcn_s_setprio(0);
  };

  auto COMPUTE2 = [&](const bf16_t* Ks, const bf16_t* Vs, int kv0) {
    float svA[16], svB[16];
    const bool noMaskB = (kv0 + 63 <= q0L + w * 16);
    __builtin_amdgcn_s_setprio(1);
#pragma unroll
    for (int ksub = 0; ksub < 4; ksub++) {
      f32x4 sa = {}, sb = {};
      const int krow = ksub * 16 + l15;
#pragma unroll
      for (int ch = 0; ch < 4; ch++) {
        bf16x8 kf = *reinterpret_cast<const bf16x8*>(
            Ks + krow * 128 + ((((ch << 2) + g) ^ (krow & 7)) << 3));
        sa = mfma16x16x32(kf, qfA[ch], sa);
        sb = mfma16x16x32(kf, qfB[ch], sb);
      }
#pragma unroll
      for (int i = 0; i < 4; i++) svA[ksub * 4 + i] = sa[i];
      if (noMaskB) {
#pragma unroll
        for (int i = 0; i < 4; i++) svB[ksub * 4 + i] = sb[i];
      } else {
        const int dltB = qrB - kv0 - ksub * 16 - (g << 2);
#pragma unroll
        for (int i = 0; i < 4; i++) svB[ksub * 4 + i] = (i <= dltB) ? sb[i] : -3e38f;
      }
    }
    __builtin_amdgcn_s_setprio(0);
    bf16x8 pcA[2], pcB[2];
    PEXP(svA, lA, pcA);
    PEXP(svB, lB, pcB);
    __builtin_amdgcn_s_setprio(1);
#pragma unroll
    for (int dt = 0; dt < 8; dt++) {
      const int vrow = dt * 16 + l15;
#pragma unroll
      for (int s = 0; s < 2; s++) {
        bf16x8 vv = *reinterpret_cast<const bf16x8*>(
            Vs + vrow * 64 + (((2 * g + s) ^ (vrow & 7)) << 3));
        oA[dt] = mfma16x16x32(vv, pcA[s], oA[dt]);
        oB[dt] = mfma16x16x32(vv, pcB[s], oB[dt]);
      }
    }
    __builtin_amdgcn_s_setprio(0);
  };

  STAGE(0, 0);
  for (int it = 0; it < ntiles; it++) {
    const int buf = it & 1;
    asm volatile("s_waitcnt vmcnt(0)" ::: "memory");
    BAR();
    if (it + 1 < ntiles) STAGE(it + 1, buf ^ 1);
    const int kv0 = it * 64;
    const bf16_t* Ks = smem[buf];
    const bf16_t* Vs = smem[buf] + 8192;
    if (kv0 <= wmaxB) {
      COMPUTE2(Ks, Vs, kv0);  // B active => A active & unmasked
    } else {
      COMPUTE1(Ks, Vs, kv0);
    }
  }
  BAR();  // all waves done with smem before epilogue reuses it
  bf16_t* os = &smem[0][0] + w * 2048;
  auto EPI = [&](f32x4* o, float lsum, int q0) {
    lsum += __shfl_xor(lsum, 16, 64);
    lsum += __shfl_xor(lsum, 32, 64);
    const float linv = 1.0f / lsum;
#pragma unroll
    for (int dt = 0; dt < 8; dt++) {
      bf16x4 pk = {(bf16_t)(o[dt][0] * linv), (bf16_t)(o[dt][1] * linv),
                   (bf16_t)(o[dt][2] * linv), (bf16_t)(o[dt][3] * linv)};
      *reinterpret_cast<bf16x4*>(os + l15 * 128 + dt * 16 + (g << 2)) = pk;
    }
    const size_t rowb = (size_t)b * SEQ_T + q0 + w * 16;
#pragma unroll
    for (int kk = 0; kk < 4; kk++) {
      const int c = lane + kk * 64;
      const int q = c >> 4, gc = c & 15;
      *reinterpret_cast<bf16x8*>(AO + (rowb + q) * DMODEL + h * HDIM + gc * 8) =
          *reinterpret_cast<const bf16x8*>(os + q * 128 + gc * 8);
    }
  };
  EPI(oA, lA, q0H);
  EPI(oB, lB, q0L);
}

extern "C" void kernel_launch(void* const* d_in, const int* in_sizes, int n_in,
                              void* d_out, int out_size, void* d_ws, size_t ws_size,
                              hipStream_t stream) {
  const float* x = (const float*)d_in[0];
  const float* Wq = (const float*)d_in[1];
  const float* Wk = (const float*)d_in[2];
  const float* Wv = (const float*)d_in[3];
  const float* Wo = (const float*)d_in[4];
  float* out = (float*)d_out;
  char* ws = (char*)d_ws;
  bf16_t* xb = (bf16_t*)(ws);                         // [4096][2048]        16 MB
  bf16_t* Wqkvb = (bf16_t*)(ws + 16777216);           // [3072][2048]        12 MB
  bf16_t* Wob = (bf16_t*)(ws + 29360128);             // [2048][2048]         8 MB
  bf16_t* Qb = (bf16_t*)(ws + 37748736);              // [2][16][2048][128]  16 MB
  bf16_t* Kb = (bf16_t*)(ws + 54525952);              // [2][4][2048][128]    4 MB
  bf16_t* Vt = (bf16_t*)(ws + 58720256);              // [2][4][128][2048]    4 MB (tp64 perm)
  bf16_t* AO = (bf16_t*)(ws + 62914560);              // [4096][2048]        16 MB
  float2* tab = (float2*)(ws + 79691776);             // [2048][64]           1 MB

  cast_all<<<9728, 256, 0, stream>>>(x, Wq, Wk, Wv, Wo, xb, Wqkvb, Wob, tab);
  gemm_qkv<<<256, 512, 0, stream>>>(xb, Wqkvb, Qb, Kb, Vt, tab);
  attn_kernel<<<dim3(32, 16), 256, 0, stream>>>(Qb, Kb, Vt, AO);
  gemm_out<<<256, 512, 0, stream>>>(AO, Wob, out);
}